// Round 4
// baseline (754.022 us; speedup 1.0000x reference)
//
#include <hip/hip_runtime.h>
#include <math.h>

#define NPTS 1024
#define NBATCH 8
#define KNN 20
#define KC 24          // candidate guard band for two-stage kNN
#define EPSBN 1e-5f
#define NSLOPE 0.2f

typedef __attribute__((ext_vector_type(8))) short short8_t;
typedef __attribute__((ext_vector_type(4))) float floatx4;

__device__ __forceinline__ float lrelu_f(float x){ return x >= 0.f ? x : NSLOPE*x; }

__device__ __forceinline__ unsigned short f2bf_rne(float f){
  union { float f; unsigned u; } x; x.f = f;
  unsigned r = x.u + 0x7FFFu + ((x.u >> 16) & 1u);
  return (unsigned short)(r >> 16);
}
__device__ __forceinline__ float bf2f(unsigned short h){
  union { float f; unsigned u; } x; x.u = ((unsigned)h) << 16;
  return x.f;
}

// ---------------- pd stage-1 (fp32): S[b,n,m] = 2*dot(x_n,x_m) - xx_m ----------------
// (per-row constant -xx_n omitted: irrelevant to per-row ranking)
__global__ __launch_bounds__(256) void pd_gemm128(const float* __restrict__ X, long bstride,
                                                  int coff, int C, float* __restrict__ PD){
  __shared__ float As[8][128];
  __shared__ float Bs[8][128];
  int b = blockIdx.z;
  int r0 = blockIdx.y * 128;
  int q0 = blockIdx.x * 128;
  int t = threadIdx.x;
  const float* Xb = X + (size_t)b*bstride + (size_t)coff*NPTS;
  float acc[8][8] = {};
  float xm2[8] = {};
  int sk = t >> 5, sn = (t & 31) << 2;
  int tr = (t >> 4) << 3, tc = (t & 15) << 3;
  for (int k0 = 0; k0 < C; k0 += 8){
    float4 av = make_float4(0,0,0,0), bv = make_float4(0,0,0,0);
    if (k0 + sk < C){
      const float* rp = Xb + (size_t)(k0+sk)*NPTS;
      av = *(const float4*)(rp + r0 + sn);
      bv = *(const float4*)(rp + q0 + sn);
    }
    *(float4*)&As[sk][sn] = av;
    *(float4*)&Bs[sk][sn] = bv;
    __syncthreads();
    #pragma unroll
    for (int kk = 0; kk < 8; ++kk){
      float4 a0 = *(const float4*)&As[kk][tr];
      float4 a1 = *(const float4*)&As[kk][tr+4];
      float4 b0 = *(const float4*)&Bs[kk][tc];
      float4 b1 = *(const float4*)&Bs[kk][tc+4];
      float a[8] = {a0.x,a0.y,a0.z,a0.w,a1.x,a1.y,a1.z,a1.w};
      float bb[8] = {b0.x,b0.y,b0.z,b0.w,b1.x,b1.y,b1.z,b1.w};
      #pragma unroll
      for (int j = 0; j < 8; ++j) xm2[j] += bb[j]*bb[j];
      #pragma unroll
      for (int i = 0; i < 8; ++i)
        #pragma unroll
        for (int j = 0; j < 8; ++j) acc[i][j] += a[i]*bb[j];
    }
    __syncthreads();
  }
  #pragma unroll
  for (int i = 0; i < 8; ++i){
    size_t base = ((size_t)b*NPTS + r0 + tr + i)*NPTS + q0 + tc;
    *(float4*)(PD + base)     = make_float4(2.f*acc[i][0]-xm2[0], 2.f*acc[i][1]-xm2[1],
                                            2.f*acc[i][2]-xm2[2], 2.f*acc[i][3]-xm2[3]);
    *(float4*)(PD + base + 4) = make_float4(2.f*acc[i][4]-xm2[4], 2.f*acc[i][5]-xm2[5],
                                            2.f*acc[i][6]-xm2[6], 2.f*acc[i][7]-xm2[7]);
  }
}

// ---------------- fused top-24 (fp32) + f64 refine -> top-20 indices ----------------
__global__ __launch_bounds__(256) void topk_refine(const float* __restrict__ PD,
                                                   const float* __restrict__ X, long bstride,
                                                   int coff, int C, int* __restrict__ IDX){
  int wid = threadIdx.x >> 6;
  int lane = threadIdx.x & 63;
  int row = blockIdx.x*4 + wid;       // b*NPTS + n
  int b = row >> 10, n = row & 1023;
  const float* p = PD + (size_t)row*NPTS;
  float v[16];
  #pragma unroll
  for (int j4 = 0; j4 < 4; ++j4){
    float4 t4 = *(const float4*)&p[lane*16 + j4*4];
    v[j4*4+0] = t4.x; v[j4*4+1] = t4.y; v[j4*4+2] = t4.z; v[j4*4+3] = t4.w;
  }
  int cand[KC];
  #pragma unroll
  for (int k = 0; k < KC; ++k){
    float bv = v[0]; int bj = 0;
    #pragma unroll
    for (int j = 1; j < 16; ++j) if (v[j] > bv){ bv = v[j]; bj = j; }
    int bi = lane*16 + bj;
    #pragma unroll
    for (int m = 1; m < 64; m <<= 1){
      float ov = __shfl_xor(bv, m, 64);
      int   oi = __shfl_xor(bi, m, 64);
      if (ov > bv || (ov == bv && oi < bi)){ bv = ov; bi = oi; }
    }
    cand[k] = bi;     // wave-uniform
    #pragma unroll
    for (int j = 0; j < 16; ++j) if (bi == lane*16 + j) v[j] = -1e38f;
  }
  // f64 refine on candidates (np op order: (2*dot - xx_m) - xx_n)
  const float* Xb = X + (size_t)b*bstride + (size_t)coff*NPTS;
  double pdv = -1e300; int midx = 1 << 20;
  if (lane < KC){
    int m = cand[lane];
    double dot = 0.0, m2 = 0.0, n2 = 0.0;
    #pragma unroll 4
    for (int c = 0; c < C; ++c){
      double xn = (double)Xb[(size_t)c*NPTS + n];
      double xm = (double)Xb[(size_t)c*NPTS + m];
      dot += xn*xm; m2 += xm*xm; n2 += xn*xn;
    }
    pdv = (2.0*dot - m2) - n2;
    midx = m;
  }
  for (int k = 0; k < KNN; ++k){
    double bv = pdv; int bi = midx;
    #pragma unroll
    for (int m = 1; m < 64; m <<= 1){
      double ov = __shfl_xor(bv, m, 64);
      int    oi = __shfl_xor(bi, m, 64);
      if (ov > bv || (ov == bv && oi < bi)){ bv = ov; bi = oi; }
    }
    if (lane == 0) IDX[(size_t)row*KNN + k] = bi;
    if (midx == bi) pdv = -1e300;
  }
}

// ---------------- OUT[b,m,n] = sum_c A[m,c]*X[b,c,n]; A rows: [0,O)=w1, [O,2O)=w2-w1 ----------------
__global__ __launch_bounds__(256) void lin_gemm128(const float* __restrict__ W, int M, int Cdim,
                                                   int lda, int O,
                                                   const float* __restrict__ X, long bstride,
                                                   int coff, float* __restrict__ OUT){
  __shared__ float As[8][64];    // As[k][m]
  __shared__ float Bs[8][128];   // Bs[k][n]
  int b = blockIdx.z;
  int m0 = blockIdx.y * 64;
  int n0 = blockIdx.x * 128;
  int t = threadIdx.x;
  const float* Xb = X + (size_t)b*bstride + (size_t)coff*NPTS;
  float acc[4][8] = {};
  int smA = t & 63, kbase = (t >> 6) << 1;
  int sk = t >> 5, sn = (t & 31) << 2;
  int tr = (t >> 4) << 2, tc = (t & 15) << 3;
  for (int k0 = 0; k0 < Cdim; k0 += 8){
    #pragma unroll
    for (int j = 0; j < 2; ++j){
      int k = kbase + j, c = k0 + k;
      float av = 0.f;
      int m = m0 + smA;
      if (c < Cdim){
        av = (m < O) ? W[(size_t)m*lda + c]
                     : W[(size_t)(m-O)*lda + Cdim + c] - W[(size_t)(m-O)*lda + c];
      }
      As[k][smA] = av;
    }
    float4 bv = make_float4(0,0,0,0);
    if (k0 + sk < Cdim)
      bv = *(const float4*)(Xb + (size_t)(k0+sk)*NPTS + n0 + sn);
    *(float4*)&Bs[sk][sn] = bv;
    __syncthreads();
    #pragma unroll
    for (int kk = 0; kk < 8; ++kk){
      float4 a0 = *(const float4*)&As[kk][tr];
      float4 b0 = *(const float4*)&Bs[kk][tc];
      float4 b1 = *(const float4*)&Bs[kk][tc+4];
      float a[4] = {a0.x,a0.y,a0.z,a0.w};
      float bb[8] = {b0.x,b0.y,b0.z,b0.w,b1.x,b1.y,b1.z,b1.w};
      #pragma unroll
      for (int i = 0; i < 4; ++i)
        #pragma unroll
        for (int j = 0; j < 8; ++j) acc[i][j] += a[i]*bb[j];
    }
    __syncthreads();
  }
  #pragma unroll
  for (int i = 0; i < 4; ++i){
    int m = m0 + tr + i;
    size_t base = ((size_t)b*M + m)*NPTS + n0 + tc;
    *(float4*)(OUT + base)     = make_float4(acc[i][0],acc[i][1],acc[i][2],acc[i][3]);
    *(float4*)(OUT + base + 4) = make_float4(acc[i][4],acc[i][5],acc[i][6],acc[i][7]);
  }
}

// ---------------- per (b,o): ymax/ymin over k of (u[n] + v[idx[n,k]]) + BN partial sums --------
__global__ void edge_stats(const float* __restrict__ V, const int* __restrict__ IDX, int O,
                           float* __restrict__ YMX, float* __restrict__ YMN,
                           float* __restrict__ S1P, float* __restrict__ S2P){
  __shared__ float vrow[NPTS];
  __shared__ float urow[NPTS];
  __shared__ float r1[256];
  __shared__ float r2[256];
  int b = blockIdx.x / O;
  int o = blockIdx.x % O;
  int t = threadIdx.x;
  const float* vp = V + ((size_t)b*2*O + o)*NPTS;
  const float* up = V + ((size_t)b*2*O + O + o)*NPTS;
  for (int i = 0; i < 4; ++i){ vrow[t+256*i] = vp[t+256*i]; urow[t+256*i] = up[t+256*i]; }
  __syncthreads();
  float s1 = 0.f, s2 = 0.f;
  size_t obase = ((size_t)b*O + o)*NPTS;
  for (int i = 0; i < 4; ++i){
    int n = t + 256*i;
    float un = urow[n];
    const int* ip = IDX + ((size_t)b*NPTS + n)*KNN;
    float mx = -1e38f, mn = 1e38f;
    #pragma unroll
    for (int k = 0; k < KNN; ++k){
      float val = un + vrow[ip[k]];
      mx = fmaxf(mx, val); mn = fminf(mn, val);
      s1 += val; s2 += val*val;
    }
    YMX[obase + n] = mx;
    YMN[obase + n] = mn;
  }
  r1[t] = s1; r2[t] = s2;
  __syncthreads();
  for (int s = 128; s > 0; s >>= 1){
    if (t < s){ r1[t] += r1[t+s]; r2[t] += r2[t+s]; }
    __syncthreads();
  }
  if (t == 0){ S1P[b*O + o] = r1[0]; S2P[b*O + o] = r2[0]; }
}

// ---------------- apply BN(inline finalize)+lrelu to max-over-k, write into CAT slice ----------------
__global__ void edge_apply(const float* __restrict__ YMX, const float* __restrict__ YMN,
                           const float* __restrict__ S1P, const float* __restrict__ S2P,
                           const float* __restrict__ gw, const float* __restrict__ gb,
                           int O, float* __restrict__ CAT, int coff_out){
  int g = blockIdx.x*blockDim.x + threadIdx.x;
  int n = g & (NPTS-1);
  int o = (g >> 10) % O;
  int b = (g >> 10) / O;
  float s1 = 0.f, s2 = 0.f;
  #pragma unroll
  for (int i = 0; i < NBATCH; ++i){ s1 += S1P[i*O + o]; s2 += S2P[i*O + o]; }
  const float cnt = (float)(NBATCH*NPTS*KNN);
  float mean = s1 / cnt;
  float var = fmaxf(s2 / cnt - mean*mean, 0.f);
  float sc = gw[o] * rsqrtf(var + EPSBN);
  float sh = gb[o] - mean*sc;
  float v = (sc >= 0.f) ? YMX[g] : YMN[g];
  CAT[((size_t)b*512 + coff_out + o)*NPTS + n] = lrelu_f(sc*v + sh);
}

// ---------------- W -> bf16 hi/lo split ----------------
__global__ void wsplit(const float* __restrict__ W, int nelem,
                       unsigned short* __restrict__ Wh, unsigned short* __restrict__ Wl){
  int i = blockIdx.x*blockDim.x + threadIdx.x;
  if (i >= nelem) return;
  float f = W[i];
  unsigned short hi = f2bf_rne(f);
  Wh[i] = hi;
  Wl[i] = f2bf_rne(f - bf2f(hi));
}

// ---------------- CAT (b,c,n) -> CATt (b,n,c) bf16 hi/lo, LDS tile transpose ----------------
__global__ void catsplit_t(const float* __restrict__ CAT,
                           unsigned short* __restrict__ Th, unsigned short* __restrict__ Tl){
  __shared__ float tile[32][33];
  int b = blockIdx.z;
  int c0 = blockIdx.y * 32;
  int n0 = blockIdx.x * 32;
  int t = threadIdx.x;
  int r = t >> 3, q = t & 7;
  float4 rv = *(const float4*)(CAT + ((size_t)b*512 + c0 + r)*NPTS + n0 + q*4);
  tile[r][q*4+0] = rv.x; tile[r][q*4+1] = rv.y; tile[r][q*4+2] = rv.z; tile[r][q*4+3] = rv.w;
  __syncthreads();
  ushort4 oh, ol;
  float f0 = tile[q*4+0][r], f1 = tile[q*4+1][r], f2 = tile[q*4+2][r], f3 = tile[q*4+3][r];
  oh.x = f2bf_rne(f0); ol.x = f2bf_rne(f0 - bf2f(oh.x));
  oh.y = f2bf_rne(f1); ol.y = f2bf_rne(f1 - bf2f(oh.y));
  oh.z = f2bf_rne(f2); ol.z = f2bf_rne(f2 - bf2f(oh.z));
  oh.w = f2bf_rne(f3); ol.w = f2bf_rne(f3 - bf2f(oh.w));
  size_t ob = ((size_t)b*NPTS + n0 + r)*512 + c0 + q*4;
  *(ushort4*)(Th + ob) = oh;
  *(ushort4*)(Tl + ob) = ol;
}

// ---------------- conv5: Y5[b,m,n] = sum_c W[m,c]*CAT[b,c,n] via bf16x3 MFMA ----------------
#define LROW 40
__global__ __launch_bounds__(256) void conv5_mfma(
    const unsigned short* __restrict__ Ath, const unsigned short* __restrict__ Atl,
    const unsigned short* __restrict__ Wh,  const unsigned short* __restrict__ Wl,
    float* __restrict__ OUT){
  __shared__ __align__(16) unsigned short Ah[128*LROW];
  __shared__ __align__(16) unsigned short Al[128*LROW];
  __shared__ __align__(16) unsigned short Bh[128*LROW];
  __shared__ __align__(16) unsigned short Bl[128*LROW];
  int b  = blockIdx.z;
  int n0 = blockIdx.x * 128;
  int m0 = blockIdx.y * 128;
  int t = threadIdx.x;
  int lane = t & 63, wid = t >> 6;
  int wn = (wid & 1) * 64;
  int wm = (wid >> 1) * 64;
  int fr = lane & 15;
  int fq = (lane >> 4) * 8;
  floatx4 acc[4][4];
  #pragma unroll
  for (int i = 0; i < 4; ++i)
    #pragma unroll
    for (int j = 0; j < 4; ++j) acc[i][j] = (floatx4)(0.f);

  for (int k0 = 0; k0 < 512; k0 += 32){
    #pragma unroll
    for (int c = 0; c < 2; ++c){
      int ch = t + 256*c;
      int row = ch >> 2, part = (ch & 3)*8;
      size_t ga = ((size_t)b*NPTS + n0 + row)*512 + k0 + part;
      size_t gb = ((size_t)(m0 + row))*512 + k0 + part;
      *(short8_t*)&Ah[row*LROW + part] = *(const short8_t*)&Ath[ga];
      *(short8_t*)&Al[row*LROW + part] = *(const short8_t*)&Atl[ga];
      *(short8_t*)&Bh[row*LROW + part] = *(const short8_t*)&Wh[gb];
      *(short8_t*)&Bl[row*LROW + part] = *(const short8_t*)&Wl[gb];
    }
    __syncthreads();
    short8_t afh[4], afl[4], bfh[4], bfl[4];
    #pragma unroll
    for (int ni = 0; ni < 4; ++ni){
      int r = (wn + ni*16 + fr)*LROW + fq;
      afh[ni] = *(const short8_t*)&Ah[r];
      afl[ni] = *(const short8_t*)&Al[r];
    }
    #pragma unroll
    for (int mi = 0; mi < 4; ++mi){
      int r = (wm + mi*16 + fr)*LROW + fq;
      bfh[mi] = *(const short8_t*)&Bh[r];
      bfl[mi] = *(const short8_t*)&Bl[r];
    }
    #pragma unroll
    for (int ni = 0; ni < 4; ++ni)
      #pragma unroll
      for (int mi = 0; mi < 4; ++mi){
        acc[ni][mi] = __builtin_amdgcn_mfma_f32_16x16x32_bf16(afh[ni], bfh[mi], acc[ni][mi], 0, 0, 0);
        acc[ni][mi] = __builtin_amdgcn_mfma_f32_16x16x32_bf16(afl[ni], bfh[mi], acc[ni][mi], 0, 0, 0);
        acc[ni][mi] = __builtin_amdgcn_mfma_f32_16x16x32_bf16(afh[ni], bfl[mi], acc[ni][mi], 0, 0, 0);
      }
    __syncthreads();
  }
  int col = lane & 15;
  int rquad = (lane >> 4) * 4;
  #pragma unroll
  for (int ni = 0; ni < 4; ++ni)
    #pragma unroll
    for (int mi = 0; mi < 4; ++mi){
      int m = m0 + wm + mi*16 + col;
      int n = n0 + wn + ni*16 + rquad;
      *(floatx4*)(OUT + ((size_t)b*1024 + m)*NPTS + n) = acc[ni][mi];
    }
}

// ---------------- conv5 BN stats ----------------
__global__ void y5_stats(const float* __restrict__ Y5, float* __restrict__ S1, float* __restrict__ S2){
  __shared__ float r1[256], r2[256];
  int o = blockIdx.x;
  int t = threadIdx.x;
  float s1 = 0.f, s2 = 0.f;
  for (int b = 0; b < NBATCH; ++b){
    const float* p = Y5 + ((size_t)b*1024 + o)*NPTS;
    for (int n = t; n < NPTS; n += 256){ float v = p[n]; s1 += v; s2 += v*v; }
  }
  r1[t] = s1; r2[t] = s2;
  __syncthreads();
  for (int s = 128; s > 0; s >>= 1){
    if (t < s){ r1[t] += r1[t+s]; r2[t] += r2[t+s]; }
    __syncthreads();
  }
  if (t == 0){ S1[o] = r1[0]; S2[o] = r2[0]; }
}

// ---------------- head: feat = [max_n, mean_n] of lrelu(BN(y5)), inline finalize ----------------
__global__ void head_kernel(const float* __restrict__ Y5, const float* __restrict__ S1,
                            const float* __restrict__ S2,
                            const float* __restrict__ gw, const float* __restrict__ gb,
                            float* __restrict__ FEAT){
  __shared__ float rm[256], rs[256];
  int o = blockIdx.x & 1023;
  int b = blockIdx.x >> 10;
  int t = threadIdx.x;
  const float cnt = (float)(NBATCH*NPTS);
  float mean = S1[o] / cnt;
  float var = fmaxf(S2[o] / cnt - mean*mean, 0.f);
  float s = gw[o] * rsqrtf(var + EPSBN);
  float sh = gb[o] - mean*s;
  const float* p = Y5 + ((size_t)b*1024 + o)*NPTS;
  float mx = -1e38f, sm = 0.f;
  for (int n = t; n < NPTS; n += 256){
    float v = lrelu_f(s*p[n] + sh);
    mx = fmaxf(mx, v); sm += v;
  }
  rm[t] = mx; rs[t] = sm;
  __syncthreads();
  for (int st = 128; st > 0; st >>= 1){
    if (t < st){ rm[t] = fmaxf(rm[t], rm[t+st]); rs[t] += rs[t+st]; }
    __syncthreads();
  }
  if (t == 0){
    FEAT[(size_t)b*2048 + o]        = rm[0];
    FEAT[(size_t)b*2048 + 1024 + o] = rs[0] * (1.f/NPTS);
  }
}

// ---------------- FC + batch-BN(8) + lrelu ----------------
__global__ void fc_bn(const float* __restrict__ IN, int ID, int OD,
                      const float* __restrict__ W, const float* __restrict__ bias,
                      const float* __restrict__ gw, const float* __restrict__ gb,
                      float* __restrict__ OUT){
  __shared__ float red[256][8];
  int f = blockIdx.x;
  int t = threadIdx.x;
  float acc[8] = {};
  const float* wr = W + (size_t)f*ID;
  for (int j = t; j < ID; j += 256){
    float wv = wr[j];
    #pragma unroll
    for (int b = 0; b < 8; ++b) acc[b] += IN[b*ID + j] * wv;
  }
  #pragma unroll
  for (int b = 0; b < 8; ++b) red[t][b] = acc[b];
  __syncthreads();
  for (int s = 128; s > 0; s >>= 1){
    if (t < s){
      #pragma unroll
      for (int b = 0; b < 8; ++b) red[t][b] += red[t+s][b];
    }
    __syncthreads();
  }
  if (t == 0){
    float h[8], mean = 0.f;
    #pragma unroll
    for (int b = 0; b < 8; ++b){ h[b] = red[0][b] + bias[f]; mean += h[b]; }
    mean *= 0.125f;
    float var = 0.f;
    #pragma unroll
    for (int b = 0; b < 8; ++b){ float d = h[b]-mean; var += d*d; }
    var *= 0.125f;
    float sc = gw[f]*rsqrtf(var + EPSBN);
    float sh = gb[f] - mean*sc;
    #pragma unroll
    for (int b = 0; b < 8; ++b) OUT[b*OD + f] = lrelu_f(sc*h[b] + sh);
  }
}

// ---------------- final linear (no BN) ----------------
__global__ void fc_out(const float* __restrict__ IN, const float* __restrict__ W,
                       const float* __restrict__ bias, float* __restrict__ OUT){
  __shared__ float red[256][8];
  int j = blockIdx.x;
  int t = threadIdx.x;
  float wv = W[(size_t)j*256 + t];
  #pragma unroll
  for (int b = 0; b < 8; ++b) red[t][b] = IN[b*256 + t] * wv;
  __syncthreads();
  for (int s = 128; s > 0; s >>= 1){
    if (t < s){
      #pragma unroll
      for (int b = 0; b < 8; ++b) red[t][b] += red[t+s][b];
    }
    __syncthreads();
  }
  if (t == 0){
    #pragma unroll
    for (int b = 0; b < 8; ++b) OUT[b*40 + j] = red[0][b] + bias[j];
  }
}

extern "C" void kernel_launch(void* const* d_in, const int* in_sizes, int n_in,
                              void* d_out, int out_size, void* d_ws, size_t ws_size,
                              hipStream_t stream) {
  const float* x   = (const float*)d_in[0];
  const float* cw[5] = { (const float*)d_in[1], (const float*)d_in[2], (const float*)d_in[3],
                         (const float*)d_in[4], (const float*)d_in[5] };
  const float* bw[7]; const float* bbv[7];
  for (int i = 0; i < 7; ++i){ bw[i] = (const float*)d_in[6+2*i]; bbv[i] = (const float*)d_in[7+2*i]; }
  const float* l1w = (const float*)d_in[20]; const float* l1b = (const float*)d_in[21];
  const float* l2w = (const float*)d_in[22]; const float* l2b = (const float*)d_in[23];
  const float* l3w = (const float*)d_in[24]; const float* l3b = (const float*)d_in[25];
  float* out = (float*)d_out;

  float* ws = (float*)d_ws;
  // Region A (0..16M floats), time-multiplexed:
  //   pd phase: PD f32 (8M); then V(4M)/YMX/YMN; conv5: Y5(8M) + bf16 bufs at +8M
  float* PD    = ws;
  float* V     = ws;
  float* YMX   = ws + 4194304;
  float* YMN   = ws + 6291456;
  float* Y5    = ws;
  unsigned short* CATth = (unsigned short*)(ws + 8388608);
  unsigned short* CATtl = (unsigned short*)(ws + 10485760);
  unsigned short* WhP   = (unsigned short*)(ws + 12582912);
  unsigned short* WlP   = (unsigned short*)(ws + 12845056);
  float* CAT   = ws + 16777216;           // (B,512,N)
  int*   IDX   = (int*)(ws + 20987904);   // 163840 ints
  float* S1P   = ws + 21151744;
  float* S2P   = ws + 21159936;
  float* FEAT  = ws + 21170176;
  float* H1    = ws + 21186560;
  float* H2    = ws + 21190656;

  struct L { int C, O; const float* in; long bs; int ci; const float* w; int bn; int co; };
  L ls[4] = {
    { 3,   64, x,   (long)3*NPTS,   0,   cw[0], 0, 0   },
    { 64,  64, CAT, (long)512*NPTS, 0,   cw[1], 1, 64  },
    { 64, 128, CAT, (long)512*NPTS, 64,  cw[2], 2, 128 },
    { 128,256, CAT, (long)512*NPTS, 128, cw[3], 3, 256 },
  };

  for (int li = 0; li < 4; ++li){
    L& l = ls[li];
    pd_gemm128<<<dim3(8,8,NBATCH), 256, 0, stream>>>(l.in, l.bs, l.ci, l.C, PD);
    topk_refine<<<(NBATCH*NPTS)/4, 256, 0, stream>>>(PD, l.in, l.bs, l.ci, l.C, IDX);
    lin_gemm128<<<dim3(8, (2*l.O)/64, NBATCH), 256, 0, stream>>>(
        l.w, 2*l.O, l.C, 2*l.C, l.O, l.in, l.bs, l.ci, V);
    edge_stats<<<NBATCH*l.O, 256, 0, stream>>>(V, IDX, l.O, YMX, YMN, S1P, S2P);
    edge_apply<<<(NBATCH*l.O*NPTS)/256, 256, 0, stream>>>(
        YMX, YMN, S1P, S2P, bw[l.bn], bbv[l.bn], l.O, CAT, l.co);
  }

  // conv5 via bf16x3 MFMA
  wsplit<<<(1024*512+255)/256, 256, 0, stream>>>(cw[4], 1024*512, WhP, WlP);
  catsplit_t<<<dim3(32,16,NBATCH), 256, 0, stream>>>(CAT, CATth, CATtl);
  conv5_mfma<<<dim3(8,8,NBATCH), 256, 0, stream>>>(CATth, CATtl, WhP, WlP, Y5);

  y5_stats<<<1024, 256, 0, stream>>>(Y5, S1P, S2P);
  head_kernel<<<NBATCH*1024, 256, 0, stream>>>(Y5, S1P, S2P, bw[4], bbv[4], FEAT);

  fc_bn<<<512, 256, 0, stream>>>(FEAT, 2048, 512, l1w, l1b, bw[5], bbv[5], H1);
  fc_bn<<<256, 256, 0, stream>>>(H1, 512, 256, l2w, l2b, bw[6], bbv[6], H2);
  fc_out<<<40, 256, 0, stream>>>(H2, l3w, l3b, out);
}

// Round 5
// 646.873 us; speedup vs baseline: 1.1656x; 1.1656x over previous
//
#include <hip/hip_runtime.h>
#include <math.h>

#define NPTS 1024
#define NBATCH 8
#define KNN 20
#define KC 24          // candidate guard band for two-stage kNN
#define EPSBN 1e-5f
#define NSLOPE 0.2f

typedef __attribute__((ext_vector_type(8))) short short8_t;
typedef __attribute__((ext_vector_type(4))) float floatx4;

__device__ __forceinline__ float lrelu_f(float x){ return x >= 0.f ? x : NSLOPE*x; }

__device__ __forceinline__ unsigned short f2bf_rne(float f){
  union { float f; unsigned u; } x; x.f = f;
  unsigned r = x.u + 0x7FFFu + ((x.u >> 16) & 1u);
  return (unsigned short)(r >> 16);
}
__device__ __forceinline__ float bf2f(unsigned short h){
  union { float f; unsigned u; } x; x.u = ((unsigned)h) << 16;
  return x.f;
}

// ---------------- pd stage-1 (fp32): S[b,n,m] = 2*dot(x_n,x_m) - xx_m ----------------
// (per-row constant -xx_n omitted: irrelevant to per-row ranking)
__global__ __launch_bounds__(256) void pd_gemm128(const float* __restrict__ X, long bstride,
                                                  int coff, int C, float* __restrict__ PD){
  __shared__ float As[8][128];
  __shared__ float Bs[8][128];
  int b = blockIdx.z;
  int r0 = blockIdx.y * 128;
  int q0 = blockIdx.x * 128;
  int t = threadIdx.x;
  const float* Xb = X + (size_t)b*bstride + (size_t)coff*NPTS;
  float acc[8][8] = {};
  float xm2[8] = {};
  int sk = t >> 5, sn = (t & 31) << 2;
  int tr = (t >> 4) << 3, tc = (t & 15) << 3;
  for (int k0 = 0; k0 < C; k0 += 8){
    float4 av = make_float4(0,0,0,0), bv = make_float4(0,0,0,0);
    if (k0 + sk < C){
      const float* rp = Xb + (size_t)(k0+sk)*NPTS;
      av = *(const float4*)(rp + r0 + sn);
      bv = *(const float4*)(rp + q0 + sn);
    }
    *(float4*)&As[sk][sn] = av;
    *(float4*)&Bs[sk][sn] = bv;
    __syncthreads();
    #pragma unroll
    for (int kk = 0; kk < 8; ++kk){
      float4 a0 = *(const float4*)&As[kk][tr];
      float4 a1 = *(const float4*)&As[kk][tr+4];
      float4 b0 = *(const float4*)&Bs[kk][tc];
      float4 b1 = *(const float4*)&Bs[kk][tc+4];
      float a[8] = {a0.x,a0.y,a0.z,a0.w,a1.x,a1.y,a1.z,a1.w};
      float bb[8] = {b0.x,b0.y,b0.z,b0.w,b1.x,b1.y,b1.z,b1.w};
      #pragma unroll
      for (int j = 0; j < 8; ++j) xm2[j] += bb[j]*bb[j];
      #pragma unroll
      for (int i = 0; i < 8; ++i)
        #pragma unroll
        for (int j = 0; j < 8; ++j) acc[i][j] += a[i]*bb[j];
    }
    __syncthreads();
  }
  #pragma unroll
  for (int i = 0; i < 8; ++i){
    size_t base = ((size_t)b*NPTS + r0 + tr + i)*NPTS + q0 + tc;
    *(float4*)(PD + base)     = make_float4(2.f*acc[i][0]-xm2[0], 2.f*acc[i][1]-xm2[1],
                                            2.f*acc[i][2]-xm2[2], 2.f*acc[i][3]-xm2[3]);
    *(float4*)(PD + base + 4) = make_float4(2.f*acc[i][4]-xm2[4], 2.f*acc[i][5]-xm2[5],
                                            2.f*acc[i][6]-xm2[6], 2.f*acc[i][7]-xm2[7]);
  }
}

// ---------------- X (b,c,n) -> XT (b,n,c) fp32, for coalesced refine loads ----------------
__global__ void xt_kernel(const float* __restrict__ X, long bstride, int coff, int C,
                          float* __restrict__ XT){
  __shared__ float tile[32][33];
  int b = blockIdx.z;
  int c0 = blockIdx.y * 32;
  int n0 = blockIdx.x * 32;
  int t = threadIdx.x;
  int r = t >> 3, q = t & 7;
  float4 rv = *(const float4*)(X + (size_t)b*bstride + (size_t)(coff+c0+r)*NPTS + n0 + q*4);
  tile[r][q*4+0] = rv.x; tile[r][q*4+1] = rv.y; tile[r][q*4+2] = rv.z; tile[r][q*4+3] = rv.w;
  __syncthreads();
  float4 ov = make_float4(tile[q*4+0][r], tile[q*4+1][r], tile[q*4+2][r], tile[q*4+3][r]);
  *(float4*)(XT + ((size_t)b*NPTS + n0 + r)*C + c0 + q*4) = ov;
}

// ---------------- fused top-24 (fp32) + f64 refine -> top-20 indices ----------------
// No register arrays with dynamic indexing: candidate k lives in lane k's registers.
__global__ __launch_bounds__(256) void topk_refine(const float* __restrict__ PD,
                                                   const float* __restrict__ X, long bstride,
                                                   int coff, int C,
                                                   const float* __restrict__ XT,
                                                   int* __restrict__ IDX){
  int wid = threadIdx.x >> 6;
  int lane = threadIdx.x & 63;
  int row = blockIdx.x*4 + wid;       // b*NPTS + n
  int b = row >> 10, n = row & 1023;
  const float* p = PD + (size_t)row*NPTS;
  float v[16];
  #pragma unroll
  for (int j4 = 0; j4 < 4; ++j4){
    float4 t4 = *(const float4*)&p[lane*16 + j4*4];
    v[j4*4+0] = t4.x; v[j4*4+1] = t4.y; v[j4*4+2] = t4.z; v[j4*4+3] = t4.w;
  }
  int my_m = 0;
  int base = lane*16;
  #pragma unroll
  for (int k = 0; k < KC; ++k){
    float bv = v[0]; int bj = 0;
    #pragma unroll
    for (int j = 1; j < 16; ++j) if (v[j] > bv){ bv = v[j]; bj = j; }
    int bi = base + bj;
    #pragma unroll
    for (int m = 1; m < 64; m <<= 1){
      float ov = __shfl_xor(bv, m, 64);
      int   oi = __shfl_xor(bi, m, 64);
      if (ov > bv || (ov == bv && oi < bi)){ bv = ov; bi = oi; }
    }
    if (lane == k) my_m = bi;          // candidate k owned by lane k
    #pragma unroll
    for (int j = 0; j < 16; ++j) v[j] = (bi == base + j) ? -1e38f : v[j];
  }
  // exact f64 recompute for this lane's candidate (np op order: (2*dot - xx_m) - xx_n)
  double pdv = -1e300; int midx = my_m;
  if (lane < KC){
    double dot = 0.0, m2 = 0.0, n2 = 0.0;
    if (C == 3){
      const float* Xb = X + (size_t)b*bstride + (size_t)coff*NPTS;
      #pragma unroll
      for (int c = 0; c < 3; ++c){
        double xn = (double)Xb[(size_t)c*NPTS + n];
        double xm = (double)Xb[(size_t)c*NPTS + my_m];
        dot += xn*xm; m2 += xm*xm; n2 += xn*xn;
      }
    } else {
      const float* rn = XT + ((size_t)b*NPTS + n)*C;      // broadcast row
      const float* rm = XT + ((size_t)b*NPTS + my_m)*C;   // per-lane contiguous row
      for (int c = 0; c < C; c += 4){
        float4 xn4 = *(const float4*)&rn[c];
        float4 xm4 = *(const float4*)&rm[c];
        dot += (double)xn4.x*(double)xm4.x + (double)xn4.y*(double)xm4.y
             + (double)xn4.z*(double)xm4.z + (double)xn4.w*(double)xm4.w;
        m2  += (double)xm4.x*(double)xm4.x + (double)xm4.y*(double)xm4.y
             + (double)xm4.z*(double)xm4.z + (double)xm4.w*(double)xm4.w;
        n2  += (double)xn4.x*(double)xn4.x + (double)xn4.y*(double)xn4.y
             + (double)xn4.z*(double)xn4.z + (double)xn4.w*(double)xn4.w;
      }
    }
    pdv = (2.0*dot - m2) - n2;
  }
  // rank among the KC candidates (value desc, index asc); unique ranks
  int rank = 0;
  #pragma unroll
  for (int j = 0; j < KC; ++j){
    double ov = __shfl(pdv, j, 64);
    int    oi = __shfl(midx, j, 64);
    rank += (ov > pdv || (ov == pdv && oi < midx)) ? 1 : 0;
  }
  if (lane < KC && rank < KNN) IDX[(size_t)row*KNN + rank] = midx;
}

// ---------------- OUT[b,m,n] = sum_c A[m,c]*X[b,c,n]; A rows: [0,O)=w1, [O,2O)=w2-w1 ----------------
__global__ __launch_bounds__(256) void lin_gemm128(const float* __restrict__ W, int M, int Cdim,
                                                   int lda, int O,
                                                   const float* __restrict__ X, long bstride,
                                                   int coff, float* __restrict__ OUT){
  __shared__ float As[8][64];    // As[k][m]
  __shared__ float Bs[8][128];   // Bs[k][n]
  int b = blockIdx.z;
  int m0 = blockIdx.y * 64;
  int n0 = blockIdx.x * 128;
  int t = threadIdx.x;
  const float* Xb = X + (size_t)b*bstride + (size_t)coff*NPTS;
  float acc[4][8] = {};
  int smA = t & 63, kbase = (t >> 6) << 1;
  int sk = t >> 5, sn = (t & 31) << 2;
  int tr = (t >> 4) << 2, tc = (t & 15) << 3;
  for (int k0 = 0; k0 < Cdim; k0 += 8){
    #pragma unroll
    for (int j = 0; j < 2; ++j){
      int k = kbase + j, c = k0 + k;
      float av = 0.f;
      int m = m0 + smA;
      if (c < Cdim){
        av = (m < O) ? W[(size_t)m*lda + c]
                     : W[(size_t)(m-O)*lda + Cdim + c] - W[(size_t)(m-O)*lda + c];
      }
      As[k][smA] = av;
    }
    float4 bv = make_float4(0,0,0,0);
    if (k0 + sk < Cdim)
      bv = *(const float4*)(Xb + (size_t)(k0+sk)*NPTS + n0 + sn);
    *(float4*)&Bs[sk][sn] = bv;
    __syncthreads();
    #pragma unroll
    for (int kk = 0; kk < 8; ++kk){
      float4 a0 = *(const float4*)&As[kk][tr];
      float4 b0 = *(const float4*)&Bs[kk][tc];
      float4 b1 = *(const float4*)&Bs[kk][tc+4];
      float a[4] = {a0.x,a0.y,a0.z,a0.w};
      float bb[8] = {b0.x,b0.y,b0.z,b0.w,b1.x,b1.y,b1.z,b1.w};
      #pragma unroll
      for (int i = 0; i < 4; ++i)
        #pragma unroll
        for (int j = 0; j < 8; ++j) acc[i][j] += a[i]*bb[j];
    }
    __syncthreads();
  }
  #pragma unroll
  for (int i = 0; i < 4; ++i){
    int m = m0 + tr + i;
    size_t base = ((size_t)b*M + m)*NPTS + n0 + tc;
    *(float4*)(OUT + base)     = make_float4(acc[i][0],acc[i][1],acc[i][2],acc[i][3]);
    *(float4*)(OUT + base + 4) = make_float4(acc[i][4],acc[i][5],acc[i][6],acc[i][7]);
  }
}

// ---------------- per (b,o): ymax/ymin over k of (u[n] + v[idx[n,k]]) + BN partial sums --------
__global__ void edge_stats(const float* __restrict__ V, const int* __restrict__ IDX, int O,
                           float* __restrict__ YMX, float* __restrict__ YMN,
                           float* __restrict__ S1P, float* __restrict__ S2P){
  __shared__ float vrow[NPTS];
  __shared__ float urow[NPTS];
  __shared__ float r1[256];
  __shared__ float r2[256];
  int b = blockIdx.x / O;
  int o = blockIdx.x % O;
  int t = threadIdx.x;
  const float* vp = V + ((size_t)b*2*O + o)*NPTS;
  const float* up = V + ((size_t)b*2*O + O + o)*NPTS;
  for (int i = 0; i < 4; ++i){ vrow[t+256*i] = vp[t+256*i]; urow[t+256*i] = up[t+256*i]; }
  __syncthreads();
  float s1 = 0.f, s2 = 0.f;
  size_t obase = ((size_t)b*O + o)*NPTS;
  for (int i = 0; i < 4; ++i){
    int n = t + 256*i;
    float un = urow[n];
    const int* ip = IDX + ((size_t)b*NPTS + n)*KNN;
    float mx = -1e38f, mn = 1e38f;
    #pragma unroll
    for (int k = 0; k < KNN; ++k){
      float val = un + vrow[ip[k]];
      mx = fmaxf(mx, val); mn = fminf(mn, val);
      s1 += val; s2 += val*val;
    }
    YMX[obase + n] = mx;
    YMN[obase + n] = mn;
  }
  r1[t] = s1; r2[t] = s2;
  __syncthreads();
  for (int s = 128; s > 0; s >>= 1){
    if (t < s){ r1[t] += r1[t+s]; r2[t] += r2[t+s]; }
    __syncthreads();
  }
  if (t == 0){ S1P[b*O + o] = r1[0]; S2P[b*O + o] = r2[0]; }
}

// ---------------- apply BN(inline finalize)+lrelu to max-over-k, write into CAT slice ----------------
__global__ void edge_apply(const float* __restrict__ YMX, const float* __restrict__ YMN,
                           const float* __restrict__ S1P, const float* __restrict__ S2P,
                           const float* __restrict__ gw, const float* __restrict__ gb,
                           int O, float* __restrict__ CAT, int coff_out){
  int g = blockIdx.x*blockDim.x + threadIdx.x;
  int n = g & (NPTS-1);
  int o = (g >> 10) % O;
  int b = (g >> 10) / O;
  float s1 = 0.f, s2 = 0.f;
  #pragma unroll
  for (int i = 0; i < NBATCH; ++i){ s1 += S1P[i*O + o]; s2 += S2P[i*O + o]; }
  const float cnt = (float)(NBATCH*NPTS*KNN);
  float mean = s1 / cnt;
  float var = fmaxf(s2 / cnt - mean*mean, 0.f);
  float sc = gw[o] * rsqrtf(var + EPSBN);
  float sh = gb[o] - mean*sc;
  float v = (sc >= 0.f) ? YMX[g] : YMN[g];
  CAT[((size_t)b*512 + coff_out + o)*NPTS + n] = lrelu_f(sc*v + sh);
}

// ---------------- W -> bf16 hi/lo split ----------------
__global__ void wsplit(const float* __restrict__ W, int nelem,
                       unsigned short* __restrict__ Wh, unsigned short* __restrict__ Wl){
  int i = blockIdx.x*blockDim.x + threadIdx.x;
  if (i >= nelem) return;
  float f = W[i];
  unsigned short hi = f2bf_rne(f);
  Wh[i] = hi;
  Wl[i] = f2bf_rne(f - bf2f(hi));
}

// ---------------- CAT (b,c,n) -> CATt (b,n,c) bf16 hi/lo, LDS tile transpose ----------------
__global__ void catsplit_t(const float* __restrict__ CAT,
                           unsigned short* __restrict__ Th, unsigned short* __restrict__ Tl){
  __shared__ float tile[32][33];
  int b = blockIdx.z;
  int c0 = blockIdx.y * 32;
  int n0 = blockIdx.x * 32;
  int t = threadIdx.x;
  int r = t >> 3, q = t & 7;
  float4 rv = *(const float4*)(CAT + ((size_t)b*512 + c0 + r)*NPTS + n0 + q*4);
  tile[r][q*4+0] = rv.x; tile[r][q*4+1] = rv.y; tile[r][q*4+2] = rv.z; tile[r][q*4+3] = rv.w;
  __syncthreads();
  ushort4 oh, ol;
  float f0 = tile[q*4+0][r], f1 = tile[q*4+1][r], f2 = tile[q*4+2][r], f3 = tile[q*4+3][r];
  oh.x = f2bf_rne(f0); ol.x = f2bf_rne(f0 - bf2f(oh.x));
  oh.y = f2bf_rne(f1); ol.y = f2bf_rne(f1 - bf2f(oh.y));
  oh.z = f2bf_rne(f2); ol.z = f2bf_rne(f2 - bf2f(oh.z));
  oh.w = f2bf_rne(f3); ol.w = f2bf_rne(f3 - bf2f(oh.w));
  size_t ob = ((size_t)b*NPTS + n0 + r)*512 + c0 + q*4;
  *(ushort4*)(Th + ob) = oh;
  *(ushort4*)(Tl + ob) = ol;
}

// ---------------- conv5: Y5[b,m,n] = sum_c W[m,c]*CAT[b,c,n] via bf16x3 MFMA ----------------
#define LROW 40
__global__ __launch_bounds__(256) void conv5_mfma(
    const unsigned short* __restrict__ Ath, const unsigned short* __restrict__ Atl,
    const unsigned short* __restrict__ Wh,  const unsigned short* __restrict__ Wl,
    float* __restrict__ OUT){
  __shared__ __align__(16) unsigned short Ah[128*LROW];
  __shared__ __align__(16) unsigned short Al[128*LROW];
  __shared__ __align__(16) unsigned short Bh[128*LROW];
  __shared__ __align__(16) unsigned short Bl[128*LROW];
  int b  = blockIdx.z;
  int n0 = blockIdx.x * 128;
  int m0 = blockIdx.y * 128;
  int t = threadIdx.x;
  int lane = t & 63, wid = t >> 6;
  int wn = (wid & 1) * 64;
  int wm = (wid >> 1) * 64;
  int fr = lane & 15;
  int fq = (lane >> 4) * 8;
  floatx4 acc[4][4];
  #pragma unroll
  for (int i = 0; i < 4; ++i)
    #pragma unroll
    for (int j = 0; j < 4; ++j) acc[i][j] = (floatx4)(0.f);

  for (int k0 = 0; k0 < 512; k0 += 32){
    #pragma unroll
    for (int c = 0; c < 2; ++c){
      int ch = t + 256*c;
      int row = ch >> 2, part = (ch & 3)*8;
      size_t ga = ((size_t)b*NPTS + n0 + row)*512 + k0 + part;
      size_t gb = ((size_t)(m0 + row))*512 + k0 + part;
      *(short8_t*)&Ah[row*LROW + part] = *(const short8_t*)&Ath[ga];
      *(short8_t*)&Al[row*LROW + part] = *(const short8_t*)&Atl[ga];
      *(short8_t*)&Bh[row*LROW + part] = *(const short8_t*)&Wh[gb];
      *(short8_t*)&Bl[row*LROW + part] = *(const short8_t*)&Wl[gb];
    }
    __syncthreads();
    short8_t afh[4], afl[4], bfh[4], bfl[4];
    #pragma unroll
    for (int ni = 0; ni < 4; ++ni){
      int r = (wn + ni*16 + fr)*LROW + fq;
      afh[ni] = *(const short8_t*)&Ah[r];
      afl[ni] = *(const short8_t*)&Al[r];
    }
    #pragma unroll
    for (int mi = 0; mi < 4; ++mi){
      int r = (wm + mi*16 + fr)*LROW + fq;
      bfh[mi] = *(const short8_t*)&Bh[r];
      bfl[mi] = *(const short8_t*)&Bl[r];
    }
    #pragma unroll
    for (int ni = 0; ni < 4; ++ni)
      #pragma unroll
      for (int mi = 0; mi < 4; ++mi){
        acc[ni][mi] = __builtin_amdgcn_mfma_f32_16x16x32_bf16(afh[ni], bfh[mi], acc[ni][mi], 0, 0, 0);
        acc[ni][mi] = __builtin_amdgcn_mfma_f32_16x16x32_bf16(afl[ni], bfh[mi], acc[ni][mi], 0, 0, 0);
        acc[ni][mi] = __builtin_amdgcn_mfma_f32_16x16x32_bf16(afh[ni], bfl[mi], acc[ni][mi], 0, 0, 0);
      }
    __syncthreads();
  }
  int col = lane & 15;
  int rquad = (lane >> 4) * 4;
  #pragma unroll
  for (int ni = 0; ni < 4; ++ni)
    #pragma unroll
    for (int mi = 0; mi < 4; ++mi){
      int m = m0 + wm + mi*16 + col;
      int n = n0 + wn + ni*16 + rquad;
      *(floatx4*)(OUT + ((size_t)b*1024 + m)*NPTS + n) = acc[ni][mi];
    }
}

// ---------------- conv5 BN stats ----------------
__global__ void y5_stats(const float* __restrict__ Y5, float* __restrict__ S1, float* __restrict__ S2){
  __shared__ float r1[256], r2[256];
  int o = blockIdx.x;
  int t = threadIdx.x;
  float s1 = 0.f, s2 = 0.f;
  for (int b = 0; b < NBATCH; ++b){
    const float* p = Y5 + ((size_t)b*1024 + o)*NPTS;
    for (int n = t; n < NPTS; n += 256){ float v = p[n]; s1 += v; s2 += v*v; }
  }
  r1[t] = s1; r2[t] = s2;
  __syncthreads();
  for (int s = 128; s > 0; s >>= 1){
    if (t < s){ r1[t] += r1[t+s]; r2[t] += r2[t+s]; }
    __syncthreads();
  }
  if (t == 0){ S1[o] = r1[0]; S2[o] = r2[0]; }
}

// ---------------- head: feat = [max_n, mean_n] of lrelu(BN(y5)), inline finalize ----------------
__global__ void head_kernel(const float* __restrict__ Y5, const float* __restrict__ S1,
                            const float* __restrict__ S2,
                            const float* __restrict__ gw, const float* __restrict__ gb,
                            float* __restrict__ FEAT){
  __shared__ float rm[256], rs[256];
  int o = blockIdx.x & 1023;
  int b = blockIdx.x >> 10;
  int t = threadIdx.x;
  const float cnt = (float)(NBATCH*NPTS);
  float mean = S1[o] / cnt;
  float var = fmaxf(S2[o] / cnt - mean*mean, 0.f);
  float s = gw[o] * rsqrtf(var + EPSBN);
  float sh = gb[o] - mean*s;
  const float* p = Y5 + ((size_t)b*1024 + o)*NPTS;
  float mx = -1e38f, sm = 0.f;
  for (int n = t; n < NPTS; n += 256){
    float v = lrelu_f(s*p[n] + sh);
    mx = fmaxf(mx, v); sm += v;
  }
  rm[t] = mx; rs[t] = sm;
  __syncthreads();
  for (int st = 128; st > 0; st >>= 1){
    if (t < st){ rm[t] = fmaxf(rm[t], rm[t+st]); rs[t] += rs[t+st]; }
    __syncthreads();
  }
  if (t == 0){
    FEAT[(size_t)b*2048 + o]        = rm[0];
    FEAT[(size_t)b*2048 + 1024 + o] = rs[0] * (1.f/NPTS);
  }
}

// ---------------- FC + batch-BN(8) + lrelu ----------------
__global__ void fc_bn(const float* __restrict__ IN, int ID, int OD,
                      const float* __restrict__ W, const float* __restrict__ bias,
                      const float* __restrict__ gw, const float* __restrict__ gb,
                      float* __restrict__ OUT){
  __shared__ float red[256][8];
  int f = blockIdx.x;
  int t = threadIdx.x;
  float acc[8] = {};
  const float* wr = W + (size_t)f*ID;
  for (int j = t; j < ID; j += 256){
    float wv = wr[j];
    #pragma unroll
    for (int b = 0; b < 8; ++b) acc[b] += IN[b*ID + j] * wv;
  }
  #pragma unroll
  for (int b = 0; b < 8; ++b) red[t][b] = acc[b];
  __syncthreads();
  for (int s = 128; s > 0; s >>= 1){
    if (t < s){
      #pragma unroll
      for (int b = 0; b < 8; ++b) red[t][b] += red[t+s][b];
    }
    __syncthreads();
  }
  if (t == 0){
    float h[8], mean = 0.f;
    #pragma unroll
    for (int b = 0; b < 8; ++b){ h[b] = red[0][b] + bias[f]; mean += h[b]; }
    mean *= 0.125f;
    float var = 0.f;
    #pragma unroll
    for (int b = 0; b < 8; ++b){ float d = h[b]-mean; var += d*d; }
    var *= 0.125f;
    float sc = gw[f]*rsqrtf(var + EPSBN);
    float sh = gb[f] - mean*sc;
    #pragma unroll
    for (int b = 0; b < 8; ++b) OUT[b*OD + f] = lrelu_f(sc*h[b] + sh);
  }
}

// ---------------- final linear (no BN) ----------------
__global__ void fc_out(const float* __restrict__ IN, const float* __restrict__ W,
                       const float* __restrict__ bias, float* __restrict__ OUT){
  __shared__ float red[256][8];
  int j = blockIdx.x;
  int t = threadIdx.x;
  float wv = W[(size_t)j*256 + t];
  #pragma unroll
  for (int b = 0; b < 8; ++b) red[t][b] = IN[b*256 + t] * wv;
  __syncthreads();
  for (int s = 128; s > 0; s >>= 1){
    if (t < s){
      #pragma unroll
      for (int b = 0; b < 8; ++b) red[t][b] += red[t+s][b];
    }
    __syncthreads();
  }
  if (t == 0){
    #pragma unroll
    for (int b = 0; b < 8; ++b) OUT[b*40 + j] = red[0][b] + bias[j];
  }
}

extern "C" void kernel_launch(void* const* d_in, const int* in_sizes, int n_in,
                              void* d_out, int out_size, void* d_ws, size_t ws_size,
                              hipStream_t stream) {
  const float* x   = (const float*)d_in[0];
  const float* cw[5] = { (const float*)d_in[1], (const float*)d_in[2], (const float*)d_in[3],
                         (const float*)d_in[4], (const float*)d_in[5] };
  const float* bw[7]; const float* bbv[7];
  for (int i = 0; i < 7; ++i){ bw[i] = (const float*)d_in[6+2*i]; bbv[i] = (const float*)d_in[7+2*i]; }
  const float* l1w = (const float*)d_in[20]; const float* l1b = (const float*)d_in[21];
  const float* l2w = (const float*)d_in[22]; const float* l2b = (const float*)d_in[23];
  const float* l3w = (const float*)d_in[24]; const float* l3b = (const float*)d_in[25];
  float* out = (float*)d_out;

  float* ws = (float*)d_ws;
  // Region A (0..16M floats), time-multiplexed:
  //   edge phase: PD f32 (8M) at 0, XT (<=1M) at +8M; then V(4M)/YMX/YMN
  //   conv5 phase: Y5(8M) at 0, bf16 bufs at +8M
  float* PD    = ws;
  float* V     = ws;
  float* YMX   = ws + 4194304;
  float* YMN   = ws + 6291456;
  float* Y5    = ws;
  float* XT    = ws + 8388608;                               // <=1M floats, edge phase only
  unsigned short* CATth = (unsigned short*)(ws + 8388608);   // conv5 phase only
  unsigned short* CATtl = (unsigned short*)(ws + 10485760);
  unsigned short* WhP   = (unsigned short*)(ws + 12582912);
  unsigned short* WlP   = (unsigned short*)(ws + 12845056);
  float* CAT   = ws + 16777216;           // (B,512,N)
  int*   IDX   = (int*)(ws + 20987904);   // 163840 ints
  float* S1P   = ws + 21151744;
  float* S2P   = ws + 21159936;
  float* FEAT  = ws + 21170176;
  float* H1    = ws + 21186560;
  float* H2    = ws + 21190656;

  struct L { int C, O; const float* in; long bs; int ci; const float* w; int bn; int co; };
  L ls[4] = {
    { 3,   64, x,   (long)3*NPTS,   0,   cw[0], 0, 0   },
    { 64,  64, CAT, (long)512*NPTS, 0,   cw[1], 1, 64  },
    { 64, 128, CAT, (long)512*NPTS, 64,  cw[2], 2, 128 },
    { 128,256, CAT, (long)512*NPTS, 128, cw[3], 3, 256 },
  };

  for (int li = 0; li < 4; ++li){
    L& l = ls[li];
    pd_gemm128<<<dim3(8,8,NBATCH), 256, 0, stream>>>(l.in, l.bs, l.ci, l.C, PD);
    if (l.C >= 32)
      xt_kernel<<<dim3(32, l.C/32, NBATCH), 256, 0, stream>>>(l.in, l.bs, l.ci, l.C, XT);
    topk_refine<<<(NBATCH*NPTS)/4, 256, 0, stream>>>(PD, l.in, l.bs, l.ci, l.C, XT, IDX);
    lin_gemm128<<<dim3(8, (2*l.O)/64, NBATCH), 256, 0, stream>>>(
        l.w, 2*l.O, l.C, 2*l.C, l.O, l.in, l.bs, l.ci, V);
    edge_stats<<<NBATCH*l.O, 256, 0, stream>>>(V, IDX, l.O, YMX, YMN, S1P, S2P);
    edge_apply<<<(NBATCH*l.O*NPTS)/256, 256, 0, stream>>>(
        YMX, YMN, S1P, S2P, bw[l.bn], bbv[l.bn], l.O, CAT, l.co);
  }

  // conv5 via bf16x3 MFMA
  wsplit<<<(1024*512+255)/256, 256, 0, stream>>>(cw[4], 1024*512, WhP, WlP);
  catsplit_t<<<dim3(32,16,NBATCH), 256, 0, stream>>>(CAT, CATth, CATtl);
  conv5_mfma<<<dim3(8,8,NBATCH), 256, 0, stream>>>(CATth, CATtl, WhP, WlP, Y5);

  y5_stats<<<1024, 256, 0, stream>>>(Y5, S1P, S2P);
  head_kernel<<<NBATCH*1024, 256, 0, stream>>>(Y5, S1P, S2P, bw[4], bbv[4], FEAT);

  fc_bn<<<512, 256, 0, stream>>>(FEAT, 2048, 512, l1w, l1b, bw[5], bbv[5], H1);
  fc_bn<<<256, 256, 0, stream>>>(H1, 512, 256, l2w, l2b, bw[6], bbv[6], H2);
  fc_out<<<40, 256, 0, stream>>>(H2, l3w, l3b, out);
}

// Round 6
// 531.348 us; speedup vs baseline: 1.4191x; 1.2174x over previous
//
#include <hip/hip_runtime.h>
#include <math.h>

#define NPTS 1024
#define NBATCH 8
#define KNN 20
#define KC 24          // candidate guard band for two-stage kNN
#define EPSBN 1e-5f
#define NSLOPE 0.2f

typedef __attribute__((ext_vector_type(8))) short short8_t;
typedef __attribute__((ext_vector_type(4))) float floatx4;

__device__ __forceinline__ float lrelu_f(float x){ return x >= 0.f ? x : NSLOPE*x; }

__device__ __forceinline__ unsigned short f2bf_rne(float f){
  union { float f; unsigned u; } x; x.f = f;
  unsigned r = x.u + 0x7FFFu + ((x.u >> 16) & 1u);
  return (unsigned short)(r >> 16);
}
__device__ __forceinline__ float bf2f(unsigned short h){
  union { float f; unsigned u; } x; x.u = ((unsigned)h) << 16;
  return x.f;
}

// ---------------- pd stage-1 (fp32): S[b,n,m] = 2*dot(x_n,x_m) - xx_m ----------------
// (per-row constant -xx_n omitted: irrelevant to per-row ranking)
__global__ __launch_bounds__(256) void pd_gemm128(const float* __restrict__ X, long bstride,
                                                  int coff, int C, float* __restrict__ PD){
  __shared__ float As[8][128];
  __shared__ float Bs[8][128];
  int b = blockIdx.z;
  int r0 = blockIdx.y * 128;
  int q0 = blockIdx.x * 128;
  int t = threadIdx.x;
  const float* Xb = X + (size_t)b*bstride + (size_t)coff*NPTS;
  float acc[8][8] = {};
  float xm2[8] = {};
  int sk = t >> 5, sn = (t & 31) << 2;
  int tr = (t >> 4) << 3, tc = (t & 15) << 3;
  for (int k0 = 0; k0 < C; k0 += 8){
    float4 av = make_float4(0,0,0,0), bv = make_float4(0,0,0,0);
    if (k0 + sk < C){
      const float* rp = Xb + (size_t)(k0+sk)*NPTS;
      av = *(const float4*)(rp + r0 + sn);
      bv = *(const float4*)(rp + q0 + sn);
    }
    *(float4*)&As[sk][sn] = av;
    *(float4*)&Bs[sk][sn] = bv;
    __syncthreads();
    #pragma unroll
    for (int kk = 0; kk < 8; ++kk){
      float4 a0 = *(const float4*)&As[kk][tr];
      float4 a1 = *(const float4*)&As[kk][tr+4];
      float4 b0 = *(const float4*)&Bs[kk][tc];
      float4 b1 = *(const float4*)&Bs[kk][tc+4];
      float a[8] = {a0.x,a0.y,a0.z,a0.w,a1.x,a1.y,a1.z,a1.w};
      float bb[8] = {b0.x,b0.y,b0.z,b0.w,b1.x,b1.y,b1.z,b1.w};
      #pragma unroll
      for (int j = 0; j < 8; ++j) xm2[j] += bb[j]*bb[j];
      #pragma unroll
      for (int i = 0; i < 8; ++i)
        #pragma unroll
        for (int j = 0; j < 8; ++j) acc[i][j] += a[i]*bb[j];
    }
    __syncthreads();
  }
  #pragma unroll
  for (int i = 0; i < 8; ++i){
    size_t base = ((size_t)b*NPTS + r0 + tr + i)*NPTS + q0 + tc;
    *(float4*)(PD + base)     = make_float4(2.f*acc[i][0]-xm2[0], 2.f*acc[i][1]-xm2[1],
                                            2.f*acc[i][2]-xm2[2], 2.f*acc[i][3]-xm2[3]);
    *(float4*)(PD + base + 4) = make_float4(2.f*acc[i][4]-xm2[4], 2.f*acc[i][5]-xm2[5],
                                            2.f*acc[i][6]-xm2[6], 2.f*acc[i][7]-xm2[7]);
  }
}

// ---------------- X (b,c,n) -> XT (b,n,c) fp32, for coalesced refine loads ----------------
__global__ void xt_kernel(const float* __restrict__ X, long bstride, int coff, int C,
                          float* __restrict__ XT){
  __shared__ float tile[32][33];
  int b = blockIdx.z;
  int c0 = blockIdx.y * 32;
  int n0 = blockIdx.x * 32;
  int t = threadIdx.x;
  int r = t >> 3, q = t & 7;
  float4 rv = *(const float4*)(X + (size_t)b*bstride + (size_t)(coff+c0+r)*NPTS + n0 + q*4);
  tile[r][q*4+0] = rv.x; tile[r][q*4+1] = rv.y; tile[r][q*4+2] = rv.z; tile[r][q*4+3] = rv.w;
  __syncthreads();
  float4 ov = make_float4(tile[q*4+0][r], tile[q*4+1][r], tile[q*4+2][r], tile[q*4+3][r]);
  *(float4*)(XT + ((size_t)b*NPTS + n0 + r)*C + c0 + q*4) = ov;
}

// ---------------- fused top-24 (sorted-list selection) + f64 refine -> top-20 ----------------
// Stage-1: per-lane 16 values -> sortable u32 keys (4-bit elem idx in low bits,
// 4 mantissa bits truncated — absorbed by guard band), bitonic-sorted descending once.
// Each round: butterfly-max of lane heads + ballot winner + winner shifts list.
__global__ __launch_bounds__(256) void topk_refine(const float* __restrict__ PD,
                                                   const float* __restrict__ X, long bstride,
                                                   int coff, int C,
                                                   const float* __restrict__ XT,
                                                   int* __restrict__ IDX){
  int wid = threadIdx.x >> 6;
  int lane = threadIdx.x & 63;
  int row = blockIdx.x*4 + wid;       // b*NPTS + n
  int b = row >> 10, n = row & 1023;
  const float* p = PD + (size_t)row*NPTS;
  unsigned key[16];
  #pragma unroll
  for (int j4 = 0; j4 < 4; ++j4){
    float4 t4 = *(const float4*)&p[lane*16 + j4*4];
    float tv[4] = {t4.x, t4.y, t4.z, t4.w};
    #pragma unroll
    for (int e = 0; e < 4; ++e){
      int j = j4*4 + e;
      unsigned u = __float_as_uint(tv[e]);
      unsigned msk = (unsigned)(((int)u) >> 31) | 0x80000000u;
      key[j] = ((u ^ msk) & 0xFFFFFFF0u) | (unsigned)j;
    }
  }
  // bitonic sort 16 keys descending (all indices compile-time after unroll)
  #pragma unroll
  for (int ksz = 2; ksz <= 16; ksz <<= 1){
    #pragma unroll
    for (int jj = ksz >> 1; jj > 0; jj >>= 1){
      #pragma unroll
      for (int i = 0; i < 16; ++i){
        int l = i ^ jj;
        if (l > i){
          unsigned a = key[i], c = key[l];
          unsigned mx = a > c ? a : c, mn = a > c ? c : a;
          bool maxfirst = ((i & ksz) == 0);
          key[i] = maxfirst ? mx : mn;
          key[l] = maxfirst ? mn : mx;
        }
      }
    }
  }
  int my_m = 0;
  #pragma unroll
  for (int k = 0; k < KC; ++k){
    unsigned h = key[0];
    unsigned gm = h;
    #pragma unroll
    for (int m = 1; m < 64; m <<= 1){
      unsigned o = (unsigned)__shfl_xor((int)gm, m, 64);
      gm = (o > gm) ? o : gm;
    }
    unsigned long long ball = __ballot(h == gm);
    int wl = __ffsll((unsigned long long)ball) - 1;
    if (lane == k) my_m = wl*16 + (int)(gm & 15u);
    bool isw = (lane == wl);
    #pragma unroll
    for (int i2 = 0; i2 < 15; ++i2) key[i2] = isw ? key[i2+1] : key[i2];
    key[15] = isw ? 0u : key[15];
  }
  // exact f64 recompute for this lane's candidate (np op order: (2*dot - xx_m) - xx_n)
  double pdv = -1e300; int midx = 1 << 20;
  if (lane < KC){
    midx = my_m;
    double dot = 0.0, m2 = 0.0, n2 = 0.0;
    if (C == 3){
      const float* Xb = X + (size_t)b*bstride + (size_t)coff*NPTS;
      #pragma unroll
      for (int c = 0; c < 3; ++c){
        double xn = (double)Xb[(size_t)c*NPTS + n];
        double xm = (double)Xb[(size_t)c*NPTS + my_m];
        dot += xn*xm; m2 += xm*xm; n2 += xn*xn;
      }
    } else {
      const float* rn = XT + ((size_t)b*NPTS + n)*C;      // broadcast row
      const float* rm = XT + ((size_t)b*NPTS + my_m)*C;   // per-lane contiguous row
      for (int c = 0; c < C; c += 4){
        float4 xn4 = *(const float4*)&rn[c];
        float4 xm4 = *(const float4*)&rm[c];
        dot += (double)xn4.x*(double)xm4.x + (double)xn4.y*(double)xm4.y
             + (double)xn4.z*(double)xm4.z + (double)xn4.w*(double)xm4.w;
        m2  += (double)xm4.x*(double)xm4.x + (double)xm4.y*(double)xm4.y
             + (double)xm4.z*(double)xm4.z + (double)xm4.w*(double)xm4.w;
        n2  += (double)xn4.x*(double)xn4.x + (double)xn4.y*(double)xn4.y
             + (double)xn4.z*(double)xn4.z + (double)xn4.w*(double)xn4.w;
      }
    }
    pdv = (2.0*dot - m2) - n2;
  }
  // rank among the KC candidates (value desc, index asc); ranks unique
  int rank = 0;
  #pragma unroll
  for (int j = 0; j < KC; ++j){
    double ov = __shfl(pdv, j, 64);
    int    oi = __shfl(midx, j, 64);
    rank += (ov > pdv || (ov == pdv && oi < midx)) ? 1 : 0;
  }
  if (lane < KC && rank < KNN) IDX[(size_t)row*KNN + rank] = midx;
}

// ---------------- OUT[b,m,n] = sum_c A[m,c]*X[b,c,n]; A rows: [0,O)=w1, [O,2O)=w2-w1 ----------------
__global__ __launch_bounds__(256) void lin_gemm128(const float* __restrict__ W, int M, int Cdim,
                                                   int lda, int O,
                                                   const float* __restrict__ X, long bstride,
                                                   int coff, float* __restrict__ OUT){
  __shared__ float As[8][64];    // As[k][m]
  __shared__ float Bs[8][128];   // Bs[k][n]
  int b = blockIdx.z;
  int m0 = blockIdx.y * 64;
  int n0 = blockIdx.x * 128;
  int t = threadIdx.x;
  const float* Xb = X + (size_t)b*bstride + (size_t)coff*NPTS;
  float acc[4][8] = {};
  int smA = t & 63, kbase = (t >> 6) << 1;
  int sk = t >> 5, sn = (t & 31) << 2;
  int tr = (t >> 4) << 2, tc = (t & 15) << 3;
  for (int k0 = 0; k0 < Cdim; k0 += 8){
    #pragma unroll
    for (int j = 0; j < 2; ++j){
      int k = kbase + j, c = k0 + k;
      float av = 0.f;
      int m = m0 + smA;
      if (c < Cdim){
        av = (m < O) ? W[(size_t)m*lda + c]
                     : W[(size_t)(m-O)*lda + Cdim + c] - W[(size_t)(m-O)*lda + c];
      }
      As[k][smA] = av;
    }
    float4 bv = make_float4(0,0,0,0);
    if (k0 + sk < Cdim)
      bv = *(const float4*)(Xb + (size_t)(k0+sk)*NPTS + n0 + sn);
    *(float4*)&Bs[sk][sn] = bv;
    __syncthreads();
    #pragma unroll
    for (int kk = 0; kk < 8; ++kk){
      float4 a0 = *(const float4*)&As[kk][tr];
      float4 b0 = *(const float4*)&Bs[kk][tc];
      float4 b1 = *(const float4*)&Bs[kk][tc+4];
      float a[4] = {a0.x,a0.y,a0.z,a0.w};
      float bb[8] = {b0.x,b0.y,b0.z,b0.w,b1.x,b1.y,b1.z,b1.w};
      #pragma unroll
      for (int i = 0; i < 4; ++i)
        #pragma unroll
        for (int j = 0; j < 8; ++j) acc[i][j] += a[i]*bb[j];
    }
    __syncthreads();
  }
  #pragma unroll
  for (int i = 0; i < 4; ++i){
    int m = m0 + tr + i;
    size_t base = ((size_t)b*M + m)*NPTS + n0 + tc;
    *(float4*)(OUT + base)     = make_float4(acc[i][0],acc[i][1],acc[i][2],acc[i][3]);
    *(float4*)(OUT + base + 4) = make_float4(acc[i][4],acc[i][5],acc[i][6],acc[i][7]);
  }
}

// ---------------- per (b,o): ymax/ymin over k of (u[n] + v[idx[n,k]]) + BN partial sums --------
__global__ void edge_stats(const float* __restrict__ V, const int* __restrict__ IDX, int O,
                           float* __restrict__ YMX, float* __restrict__ YMN,
                           float* __restrict__ S1P, float* __restrict__ S2P){
  __shared__ float vrow[NPTS];
  __shared__ float urow[NPTS];
  __shared__ float r1[256];
  __shared__ float r2[256];
  int b = blockIdx.x / O;
  int o = blockIdx.x % O;
  int t = threadIdx.x;
  const float* vp = V + ((size_t)b*2*O + o)*NPTS;
  const float* up = V + ((size_t)b*2*O + O + o)*NPTS;
  for (int i = 0; i < 4; ++i){ vrow[t+256*i] = vp[t+256*i]; urow[t+256*i] = up[t+256*i]; }
  __syncthreads();
  float s1 = 0.f, s2 = 0.f;
  size_t obase = ((size_t)b*O + o)*NPTS;
  for (int i = 0; i < 4; ++i){
    int n = t + 256*i;
    float un = urow[n];
    const int* ip = IDX + ((size_t)b*NPTS + n)*KNN;
    float mx = -1e38f, mn = 1e38f;
    #pragma unroll
    for (int k = 0; k < KNN; ++k){
      float val = un + vrow[ip[k]];
      mx = fmaxf(mx, val); mn = fminf(mn, val);
      s1 += val; s2 += val*val;
    }
    YMX[obase + n] = mx;
    YMN[obase + n] = mn;
  }
  r1[t] = s1; r2[t] = s2;
  __syncthreads();
  for (int s = 128; s > 0; s >>= 1){
    if (t < s){ r1[t] += r1[t+s]; r2[t] += r2[t+s]; }
    __syncthreads();
  }
  if (t == 0){ S1P[b*O + o] = r1[0]; S2P[b*O + o] = r2[0]; }
}

// ---------------- apply BN(inline finalize)+lrelu to max-over-k, write into CAT slice ----------------
__global__ void edge_apply(const float* __restrict__ YMX, const float* __restrict__ YMN,
                           const float* __restrict__ S1P, const float* __restrict__ S2P,
                           const float* __restrict__ gw, const float* __restrict__ gb,
                           int O, float* __restrict__ CAT, int coff_out){
  int g = blockIdx.x*blockDim.x + threadIdx.x;
  int n = g & (NPTS-1);
  int o = (g >> 10) % O;
  int b = (g >> 10) / O;
  float s1 = 0.f, s2 = 0.f;
  #pragma unroll
  for (int i = 0; i < NBATCH; ++i){ s1 += S1P[i*O + o]; s2 += S2P[i*O + o]; }
  const float cnt = (float)(NBATCH*NPTS*KNN);
  float mean = s1 / cnt;
  float var = fmaxf(s2 / cnt - mean*mean, 0.f);
  float sc = gw[o] * rsqrtf(var + EPSBN);
  float sh = gb[o] - mean*sc;
  float v = (sc >= 0.f) ? YMX[g] : YMN[g];
  CAT[((size_t)b*512 + coff_out + o)*NPTS + n] = lrelu_f(sc*v + sh);
}

// ---------------- W -> bf16 hi/lo split ----------------
__global__ void wsplit(const float* __restrict__ W, int nelem,
                       unsigned short* __restrict__ Wh, unsigned short* __restrict__ Wl){
  int i = blockIdx.x*blockDim.x + threadIdx.x;
  if (i >= nelem) return;
  float f = W[i];
  unsigned short hi = f2bf_rne(f);
  Wh[i] = hi;
  Wl[i] = f2bf_rne(f - bf2f(hi));
}

// ---------------- CAT (b,c,n) -> CATt (b,n,c) bf16 hi/lo, LDS tile transpose ----------------
__global__ void catsplit_t(const float* __restrict__ CAT,
                           unsigned short* __restrict__ Th, unsigned short* __restrict__ Tl){
  __shared__ float tile[32][33];
  int b = blockIdx.z;
  int c0 = blockIdx.y * 32;
  int n0 = blockIdx.x * 32;
  int t = threadIdx.x;
  int r = t >> 3, q = t & 7;
  float4 rv = *(const float4*)(CAT + ((size_t)b*512 + c0 + r)*NPTS + n0 + q*4);
  tile[r][q*4+0] = rv.x; tile[r][q*4+1] = rv.y; tile[r][q*4+2] = rv.z; tile[r][q*4+3] = rv.w;
  __syncthreads();
  ushort4 oh, ol;
  float f0 = tile[q*4+0][r], f1 = tile[q*4+1][r], f2 = tile[q*4+2][r], f3 = tile[q*4+3][r];
  oh.x = f2bf_rne(f0); ol.x = f2bf_rne(f0 - bf2f(oh.x));
  oh.y = f2bf_rne(f1); ol.y = f2bf_rne(f1 - bf2f(oh.y));
  oh.z = f2bf_rne(f2); ol.z = f2bf_rne(f2 - bf2f(oh.z));
  oh.w = f2bf_rne(f3); ol.w = f2bf_rne(f3 - bf2f(oh.w));
  size_t ob = ((size_t)b*NPTS + n0 + r)*512 + c0 + q*4;
  *(ushort4*)(Th + ob) = oh;
  *(ushort4*)(Tl + ob) = ol;
}

// ---------------- conv5: Y5[b,m,n] = sum_c W[m,c]*CAT[b,c,n] via bf16x3 MFMA ----------------
#define LROW 40
__global__ __launch_bounds__(256) void conv5_mfma(
    const unsigned short* __restrict__ Ath, const unsigned short* __restrict__ Atl,
    const unsigned short* __restrict__ Wh,  const unsigned short* __restrict__ Wl,
    float* __restrict__ OUT){
  __shared__ __align__(16) unsigned short Ah[128*LROW];
  __shared__ __align__(16) unsigned short Al[128*LROW];
  __shared__ __align__(16) unsigned short Bh[128*LROW];
  __shared__ __align__(16) unsigned short Bl[128*LROW];
  int b  = blockIdx.z;
  int n0 = blockIdx.x * 128;
  int m0 = blockIdx.y * 128;
  int t = threadIdx.x;
  int lane = t & 63, wid = t >> 6;
  int wn = (wid & 1) * 64;
  int wm = (wid >> 1) * 64;
  int fr = lane & 15;
  int fq = (lane >> 4) * 8;
  floatx4 acc[4][4];
  #pragma unroll
  for (int i = 0; i < 4; ++i)
    #pragma unroll
    for (int j = 0; j < 4; ++j) acc[i][j] = (floatx4)(0.f);

  for (int k0 = 0; k0 < 512; k0 += 32){
    #pragma unroll
    for (int c = 0; c < 2; ++c){
      int ch = t + 256*c;
      int row = ch >> 2, part = (ch & 3)*8;
      size_t ga = ((size_t)b*NPTS + n0 + row)*512 + k0 + part;
      size_t gb = ((size_t)(m0 + row))*512 + k0 + part;
      *(short8_t*)&Ah[row*LROW + part] = *(const short8_t*)&Ath[ga];
      *(short8_t*)&Al[row*LROW + part] = *(const short8_t*)&Atl[ga];
      *(short8_t*)&Bh[row*LROW + part] = *(const short8_t*)&Wh[gb];
      *(short8_t*)&Bl[row*LROW + part] = *(const short8_t*)&Wl[gb];
    }
    __syncthreads();
    short8_t afh[4], afl[4], bfh[4], bfl[4];
    #pragma unroll
    for (int ni = 0; ni < 4; ++ni){
      int r = (wn + ni*16 + fr)*LROW + fq;
      afh[ni] = *(const short8_t*)&Ah[r];
      afl[ni] = *(const short8_t*)&Al[r];
    }
    #pragma unroll
    for (int mi = 0; mi < 4; ++mi){
      int r = (wm + mi*16 + fr)*LROW + fq;
      bfh[mi] = *(const short8_t*)&Bh[r];
      bfl[mi] = *(const short8_t*)&Bl[r];
    }
    #pragma unroll
    for (int ni = 0; ni < 4; ++ni)
      #pragma unroll
      for (int mi = 0; mi < 4; ++mi){
        acc[ni][mi] = __builtin_amdgcn_mfma_f32_16x16x32_bf16(afh[ni], bfh[mi], acc[ni][mi], 0, 0, 0);
        acc[ni][mi] = __builtin_amdgcn_mfma_f32_16x16x32_bf16(afl[ni], bfh[mi], acc[ni][mi], 0, 0, 0);
        acc[ni][mi] = __builtin_amdgcn_mfma_f32_16x16x32_bf16(afh[ni], bfl[mi], acc[ni][mi], 0, 0, 0);
      }
    __syncthreads();
  }
  int col = lane & 15;
  int rquad = (lane >> 4) * 4;
  #pragma unroll
  for (int ni = 0; ni < 4; ++ni)
    #pragma unroll
    for (int mi = 0; mi < 4; ++mi){
      int m = m0 + wm + mi*16 + col;
      int n = n0 + wn + ni*16 + rquad;
      *(floatx4*)(OUT + ((size_t)b*1024 + m)*NPTS + n) = acc[ni][mi];
    }
}

// ---------------- conv5 BN stats ----------------
__global__ void y5_stats(const float* __restrict__ Y5, float* __restrict__ S1, float* __restrict__ S2){
  __shared__ float r1[256], r2[256];
  int o = blockIdx.x;
  int t = threadIdx.x;
  float s1 = 0.f, s2 = 0.f;
  for (int b = 0; b < NBATCH; ++b){
    const float* p = Y5 + ((size_t)b*1024 + o)*NPTS;
    for (int n = t; n < NPTS; n += 256){ float v = p[n]; s1 += v; s2 += v*v; }
  }
  r1[t] = s1; r2[t] = s2;
  __syncthreads();
  for (int s = 128; s > 0; s >>= 1){
    if (t < s){ r1[t] += r1[t+s]; r2[t] += r2[t+s]; }
    __syncthreads();
  }
  if (t == 0){ S1[o] = r1[0]; S2[o] = r2[0]; }
}

// ---------------- head: feat = [max_n, mean_n] of lrelu(BN(y5)), inline finalize ----------------
__global__ void head_kernel(const float* __restrict__ Y5, const float* __restrict__ S1,
                            const float* __restrict__ S2,
                            const float* __restrict__ gw, const float* __restrict__ gb,
                            float* __restrict__ FEAT){
  __shared__ float rm[256], rs[256];
  int o = blockIdx.x & 1023;
  int b = blockIdx.x >> 10;
  int t = threadIdx.x;
  const float cnt = (float)(NBATCH*NPTS);
  float mean = S1[o] / cnt;
  float var = fmaxf(S2[o] / cnt - mean*mean, 0.f);
  float s = gw[o] * rsqrtf(var + EPSBN);
  float sh = gb[o] - mean*s;
  const float* p = Y5 + ((size_t)b*1024 + o)*NPTS;
  float mx = -1e38f, sm = 0.f;
  for (int n = t; n < NPTS; n += 256){
    float v = lrelu_f(s*p[n] + sh);
    mx = fmaxf(mx, v); sm += v;
  }
  rm[t] = mx; rs[t] = sm;
  __syncthreads();
  for (int st = 128; st > 0; st >>= 1){
    if (t < st){ rm[t] = fmaxf(rm[t], rm[t+st]); rs[t] += rs[t+st]; }
    __syncthreads();
  }
  if (t == 0){
    FEAT[(size_t)b*2048 + o]        = rm[0];
    FEAT[(size_t)b*2048 + 1024 + o] = rs[0] * (1.f/NPTS);
  }
}

// ---------------- FC + batch-BN(8) + lrelu ----------------
__global__ void fc_bn(const float* __restrict__ IN, int ID, int OD,
                      const float* __restrict__ W, const float* __restrict__ bias,
                      const float* __restrict__ gw, const float* __restrict__ gb,
                      float* __restrict__ OUT){
  __shared__ float red[256][8];
  int f = blockIdx.x;
  int t = threadIdx.x;
  float acc[8] = {};
  const float* wr = W + (size_t)f*ID;
  for (int j = t; j < ID; j += 256){
    float wv = wr[j];
    #pragma unroll
    for (int b = 0; b < 8; ++b) acc[b] += IN[b*ID + j] * wv;
  }
  #pragma unroll
  for (int b = 0; b < 8; ++b) red[t][b] = acc[b];
  __syncthreads();
  for (int s = 128; s > 0; s >>= 1){
    if (t < s){
      #pragma unroll
      for (int b = 0; b < 8; ++b) red[t][b] += red[t+s][b];
    }
    __syncthreads();
  }
  if (t == 0){
    float h[8], mean = 0.f;
    #pragma unroll
    for (int b = 0; b < 8; ++b){ h[b] = red[0][b] + bias[f]; mean += h[b]; }
    mean *= 0.125f;
    float var = 0.f;
    #pragma unroll
    for (int b = 0; b < 8; ++b){ float d = h[b]-mean; var += d*d; }
    var *= 0.125f;
    float sc = gw[f]*rsqrtf(var + EPSBN);
    float sh = gb[f] - mean*sc;
    #pragma unroll
    for (int b = 0; b < 8; ++b) OUT[b*OD + f] = lrelu_f(sc*h[b] + sh);
  }
}

// ---------------- final linear (no BN) ----------------
__global__ void fc_out(const float* __restrict__ IN, const float* __restrict__ W,
                       const float* __restrict__ bias, float* __restrict__ OUT){
  __shared__ float red[256][8];
  int j = blockIdx.x;
  int t = threadIdx.x;
  float wv = W[(size_t)j*256 + t];
  #pragma unroll
  for (int b = 0; b < 8; ++b) red[t][b] = IN[b*256 + t] * wv;
  __syncthreads();
  for (int s = 128; s > 0; s >>= 1){
    if (t < s){
      #pragma unroll
      for (int b = 0; b < 8; ++b) red[t][b] += red[t+s][b];
    }
    __syncthreads();
  }
  if (t == 0){
    #pragma unroll
    for (int b = 0; b < 8; ++b) OUT[b*40 + j] = red[0][b] + bias[j];
  }
}

extern "C" void kernel_launch(void* const* d_in, const int* in_sizes, int n_in,
                              void* d_out, int out_size, void* d_ws, size_t ws_size,
                              hipStream_t stream) {
  const float* x   = (const float*)d_in[0];
  const float* cw[5] = { (const float*)d_in[1], (const float*)d_in[2], (const float*)d_in[3],
                         (const float*)d_in[4], (const float*)d_in[5] };
  const float* bw[7]; const float* bbv[7];
  for (int i = 0; i < 7; ++i){ bw[i] = (const float*)d_in[6+2*i]; bbv[i] = (const float*)d_in[7+2*i]; }
  const float* l1w = (const float*)d_in[20]; const float* l1b = (const float*)d_in[21];
  const float* l2w = (const float*)d_in[22]; const float* l2b = (const float*)d_in[23];
  const float* l3w = (const float*)d_in[24]; const float* l3b = (const float*)d_in[25];
  float* out = (float*)d_out;

  float* ws = (float*)d_ws;
  // Region A (0..16M floats), time-multiplexed:
  //   edge phase: PD f32 (8M) at 0, XT (<=1M) at +8M; then V(4M)/YMX/YMN
  //   conv5 phase: Y5(8M) at 0, bf16 bufs at +8M
  float* PD    = ws;
  float* V     = ws;
  float* YMX   = ws + 4194304;
  float* YMN   = ws + 6291456;
  float* Y5    = ws;
  float* XT    = ws + 8388608;                               // <=1M floats, edge phase only
  unsigned short* CATth = (unsigned short*)(ws + 8388608);   // conv5 phase only
  unsigned short* CATtl = (unsigned short*)(ws + 10485760);
  unsigned short* WhP   = (unsigned short*)(ws + 12582912);
  unsigned short* WlP   = (unsigned short*)(ws + 12845056);
  float* CAT   = ws + 16777216;           // (B,512,N)
  int*   IDX   = (int*)(ws + 20987904);   // 163840 ints
  float* S1P   = ws + 21151744;
  float* S2P   = ws + 21159936;
  float* FEAT  = ws + 21170176;
  float* H1    = ws + 21186560;
  float* H2    = ws + 21190656;

  struct L { int C, O; const float* in; long bs; int ci; const float* w; int bn; int co; };
  L ls[4] = {
    { 3,   64, x,   (long)3*NPTS,   0,   cw[0], 0, 0   },
    { 64,  64, CAT, (long)512*NPTS, 0,   cw[1], 1, 64  },
    { 64, 128, CAT, (long)512*NPTS, 64,  cw[2], 2, 128 },
    { 128,256, CAT, (long)512*NPTS, 128, cw[3], 3, 256 },
  };

  for (int li = 0; li < 4; ++li){
    L& l = ls[li];
    pd_gemm128<<<dim3(8,8,NBATCH), 256, 0, stream>>>(l.in, l.bs, l.ci, l.C, PD);
    if (l.C >= 32)
      xt_kernel<<<dim3(32, l.C/32, NBATCH), 256, 0, stream>>>(l.in, l.bs, l.ci, l.C, XT);
    topk_refine<<<(NBATCH*NPTS)/4, 256, 0, stream>>>(PD, l.in, l.bs, l.ci, l.C, XT, IDX);
    lin_gemm128<<<dim3(8, (2*l.O)/64, NBATCH), 256, 0, stream>>>(
        l.w, 2*l.O, l.C, 2*l.C, l.O, l.in, l.bs, l.ci, V);
    edge_stats<<<NBATCH*l.O, 256, 0, stream>>>(V, IDX, l.O, YMX, YMN, S1P, S2P);
    edge_apply<<<(NBATCH*l.O*NPTS)/256, 256, 0, stream>>>(
        YMX, YMN, S1P, S2P, bw[l.bn], bbv[l.bn], l.O, CAT, l.co);
  }

  // conv5 via bf16x3 MFMA
  wsplit<<<(1024*512+255)/256, 256, 0, stream>>>(cw[4], 1024*512, WhP, WlP);
  catsplit_t<<<dim3(32,16,NBATCH), 256, 0, stream>>>(CAT, CATth, CATtl);
  conv5_mfma<<<dim3(8,8,NBATCH), 256, 0, stream>>>(CATth, CATtl, WhP, WlP, Y5);

  y5_stats<<<1024, 256, 0, stream>>>(Y5, S1P, S2P);
  head_kernel<<<NBATCH*1024, 256, 0, stream>>>(Y5, S1P, S2P, bw[4], bbv[4], FEAT);

  fc_bn<<<512, 256, 0, stream>>>(FEAT, 2048, 512, l1w, l1b, bw[5], bbv[5], H1);
  fc_bn<<<256, 256, 0, stream>>>(H1, 512, 256, l2w, l2b, bw[6], bbv[6], H2);
  fc_out<<<40, 256, 0, stream>>>(H2, l3w, l3b, out);
}